// Round 1
// baseline (1114.400 us; speedup 1.0000x reference)
//
#include <hip/hip_runtime.h>
#include <stdint.h>
#include <stddef.h>

#define T_   4096
#define BT_  8192
#define SCALING_F      0.04419417382415922f
#define LAMBDA_INIT_F  0.7836057665316212f
#define ONE_MINUS_LI_F 0.2163942334683788f

typedef __attribute__((ext_vector_type(8))) short short8;
typedef __attribute__((ext_vector_type(4))) short short4v;
typedef __attribute__((ext_vector_type(4))) float f32x4;

__device__ __forceinline__ short f2bf(float f){
  uint32_t u = __float_as_uint(f);
  uint32_t r = (u + 0x7fffu + ((u >> 16) & 1u)) >> 16;   // RNE
  return (short)(uint16_t)r;
}

__device__ __forceinline__ f32x4 mfma16(short8 a, short8 b, f32x4 c){
  return __builtin_amdgcn_mfma_f32_16x16x32_bf16(a, b, c, 0, 0, 0);
}

__device__ __forceinline__ void stage16(short* lds, const short* g){
  __builtin_amdgcn_global_load_lds(
      (const __attribute__((address_space(1))) void*)g,
      (__attribute__((address_space(3))) void*)lds, 16, 0, 0);
}

// ---------------- fp32 -> bf16 convert ----------------
__global__ void k_cvt(const float* __restrict__ in, short* __restrict__ out, int n4){
  int i  = blockIdx.x*blockDim.x + threadIdx.x;
  int st = gridDim.x*blockDim.x;
  for (; i < n4; i += st){
    float4 v = ((const float4*)in)[i];
    short4v o;
    o.x = f2bf(v.x); o.y = f2bf(v.y); o.z = f2bf(v.z); o.w = f2bf(v.w);
    ((short4v*)out)[i] = o;
  }
}

// ---------------- NT GEMM: C[m][n] = sum_k A[m][k]*B[n][k], K=1024 fixed ----
// EPI: 0 = bf16 out, 1 = bf16 out * SCALING, 2 = fp32 out
template<int EPI>
__global__ __launch_bounds__(256, 3) void k_gemm(const short* __restrict__ A,
                                                 const short* __restrict__ Bm,
                                                 void* __restrict__ Cp, int ldc){
  __shared__ short As[128*32];
  __shared__ short Bs[128*32];
  const int tid = threadIdx.x;
  const int w = tid >> 6, l = tid & 63;
  const int m0 = blockIdx.x * 128;
  const int n0 = blockIdx.y * 128;
  const int wr = w >> 1, wc = w & 1;

  f32x4 acc[4][4] = {};

  // staging: wave w covers rows [w*32, w*32+32) in 2 chunks of 16 rows
  const short* gA = A  + (size_t)(m0 + w*32 + (l>>2))*1024 + (l&3)*8;
  const short* gB = Bm + (size_t)(n0 + w*32 + (l>>2))*1024 + (l&3)*8;

  for (int k0 = 0; k0 < 1024; k0 += 32){
    stage16(As + w*1024,       gA + k0);
    stage16(As + w*1024 + 512, gA + 16*1024 + k0);
    stage16(Bs + w*1024,       gB + k0);
    stage16(Bs + w*1024 + 512, gB + 16*1024 + k0);
    __syncthreads();
    short8 aF[4], bF[4];
    #pragma unroll
    for (int i = 0; i < 4; i++){
      aF[i] = *(const short8*)&As[(wr*64 + i*16 + (l&15))*32 + (l>>4)*8];
      bF[i] = *(const short8*)&Bs[(wc*64 + i*16 + (l&15))*32 + (l>>4)*8];
    }
    #pragma unroll
    for (int i = 0; i < 4; i++)
      #pragma unroll
      for (int j = 0; j < 4; j++)
        acc[i][j] = mfma16(aF[i], bF[j], acc[i][j]);
    __syncthreads();
  }

  #pragma unroll
  for (int i = 0; i < 4; i++){
    #pragma unroll
    for (int j = 0; j < 4; j++){
      const size_t r0 = (size_t)m0 + wr*64 + i*16 + (l>>4)*4;
      const size_t c  = (size_t)n0 + wc*64 + j*16 + (l&15);
      #pragma unroll
      for (int rg = 0; rg < 4; rg++){
        float v = acc[i][j][rg];
        if (EPI == 2){
          ((float*)Cp)[(r0+rg)*(size_t)ldc + c] = v;
        } else {
          if (EPI == 1) v *= SCALING_F;
          ((short*)Cp)[(r0+rg)*(size_t)ldc + c] = f2bf(v);
        }
      }
    }
  }
}

// ---------------- fused dual-softmax attention + RMSNorm ----------------
// grid: (T/32, B), block 512 (8 waves). QP [BT][1024] (pre-scaled), KP [BT][512],
// VPT [1024][BT] (vp transposed), out Ab [BT][1024] bf16 (normed attn).
__global__ __launch_bounds__(512, 2) void k_attn(
    const short* __restrict__ QP, const short* __restrict__ KP,
    const short* __restrict__ VPT,
    const float* __restrict__ lq1, const float* __restrict__ lk1,
    const float* __restrict__ lq2, const float* __restrict__ lk2,
    short* __restrict__ Ab)
{
  __shared__ short Pl[2][32][88];   // exp(S) tiles, 176B row stride (16B-aligned)
  __shared__ float lsum[8][16];
  __shared__ float rinv[2][32];
  __shared__ float ssq[4][32];

  const int b  = blockIdx.y;
  const int t0 = blockIdx.x * 32;
  const int tid = threadIdx.x;
  const int w = tid >> 6, l = tid & 63;

  // lambda = exp(lq1.lk1) - exp(lq2.lk2) + LAMBDA_INIT (each wave redundantly)
  float s1 = 0.f, s2 = 0.f;
  #pragma unroll
  for (int i = 0; i < 8; i++){
    int idx = l*8 + i;
    s1 += lq1[idx]*lk1[idx];
    s2 += lq2[idx]*lk2[idx];
  }
  #pragma unroll
  for (int off = 1; off < 64; off <<= 1){
    s1 += __shfl_xor(s1, off, 64);
    s2 += __shfl_xor(s2, off, 64);
  }
  const float lam = __expf(s1) - __expf(s2) + LAMBDA_INIT_F;

  // phase-1 role: rc selects (head, t-chunk); scb selects s-chunk pair
  const int rc = w >> 1, h = rc >> 1, tch = rc & 1, scb = (w & 1)*2;
  short8 qF[16];
  {
    const short* qb = QP + (size_t)(b*T_ + t0 + tch*16 + (l&15))*1024 + h*512 + (l>>4)*8;
    #pragma unroll
    for (int kk = 0; kk < 16; kk++) qF[kk] = *(const short8*)(qb + kk*32);
  }

  // phase-2 role: wr = t-half, wc = 256-wide d-column slice
  const int wr = w >> 2, wc = w & 3;
  f32x4 acc1[16], acc2[16];
  #pragma unroll
  for (int i = 0; i < 16; i++){
    acc1[i] = (f32x4){0.f,0.f,0.f,0.f};
    acc2[i] = (f32x4){0.f,0.f,0.f,0.f};
  }
  float lacc[4] = {0.f,0.f,0.f,0.f};

  const short* kbase = KP  + (size_t)(b*T_)*512 + (l>>4)*8;
  const short* vbase = VPT + (size_t)(wc*256 + (l&15))*BT_ + b*T_ + (l>>4)*8;

  for (int st = 0; st < 64; st++){
    const int s0 = st*64;
    // ---- phase 1: S = Q.K^T (stacked 64 rows = 2h x 32t), exp -> LDS ----
    {
      const short* kb0 = kbase + (size_t)(s0 + scb*16 + (l&15))*512;
      const short* kb1 = kb0 + (size_t)16*512;
      f32x4 sa0 = {0.f,0.f,0.f,0.f}, sa1 = {0.f,0.f,0.f,0.f};
      #pragma unroll
      for (int kk = 0; kk < 16; kk++){
        short8 b0 = *(const short8*)(kb0 + kk*32);
        short8 b1 = *(const short8*)(kb1 + kk*32);
        sa0 = mfma16(qF[kk], b0, sa0);
        sa1 = mfma16(qF[kk], b1, sa1);
      }
      #pragma unroll
      for (int rg = 0; rg < 4; rg++){
        float e0 = __expf(sa0[rg]);
        float e1 = __expf(sa1[rg]);
        lacc[rg] += e0 + e1;
        int row = tch*16 + (l>>4)*4 + rg;
        Pl[h][row][(scb+0)*16 + (l&15)] = f2bf(e0);
        Pl[h][row][(scb+1)*16 + (l&15)] = f2bf(e1);
      }
    }
    __syncthreads();
    // ---- phase 2: O1 += P1.V, O2 += P2.V (V from VPT, k-contiguous) ----
    #pragma unroll
    for (int ks = 0; ks < 2; ks++){
      short8 a1 = *(const short8*)&Pl[0][wr*16 + (l&15)][ks*32 + (l>>4)*8];
      short8 a2 = *(const short8*)&Pl[1][wr*16 + (l&15)][ks*32 + (l>>4)*8];
      #pragma unroll
      for (int dc = 0; dc < 16; dc++){
        short8 bV = *(const short8*)(vbase + (size_t)dc*16*BT_ + s0 + ks*32);
        acc1[dc] = mfma16(a1, bV, acc1[dc]);
        acc2[dc] = mfma16(a2, bV, acc2[dc]);
      }
    }
    __syncthreads();
  }

  // ---- row sums -> 1/l ----
  #pragma unroll
  for (int off = 1; off < 16; off <<= 1)
    #pragma unroll
    for (int rg = 0; rg < 4; rg++) lacc[rg] += __shfl_xor(lacc[rg], off, 16);
  if ((l & 15) == 0){
    #pragma unroll
    for (int rg = 0; rg < 4; rg++) lsum[w][(l>>4)*4 + rg] = lacc[rg];
  }
  __syncthreads();
  if (tid < 64){
    int hh = tid >> 5, t = tid & 31;
    int rcc = hh*2 + (t >> 4), ric = t & 15;
    rinv[hh][t] = 1.0f / (lsum[rcc*2][ric] + lsum[rcc*2+1][ric]);
  }
  __syncthreads();

  // ---- combine pass 1: row sum-of-squares for RMSNorm ----
  float ps[4] = {0.f,0.f,0.f,0.f};
  #pragma unroll
  for (int dc = 0; dc < 16; dc++){
    #pragma unroll
    for (int rg = 0; rg < 4; rg++){
      int t32 = wr*16 + (l>>4)*4 + rg;
      float o = acc1[dc][rg]*rinv[0][t32] - lam*acc2[dc][rg]*rinv[1][t32];
      ps[rg] += o*o;
    }
  }
  #pragma unroll
  for (int off = 1; off < 16; off <<= 1)
    #pragma unroll
    for (int rg = 0; rg < 4; rg++) ps[rg] += __shfl_xor(ps[rg], off, 16);
  if ((l & 15) == 0){
    #pragma unroll
    for (int rg = 0; rg < 4; rg++) ssq[wc][wr*16 + (l>>4)*4 + rg] = ps[rg];
  }
  __syncthreads();

  // ---- combine pass 2: normalize + store bf16 ----
  #pragma unroll
  for (int rg = 0; rg < 4; rg++){
    int t32 = wr*16 + (l>>4)*4 + rg;
    float tot = ssq[0][t32] + ssq[1][t32] + ssq[2][t32] + ssq[3][t32];
    float scale = rsqrtf(tot*(1.0f/1024.0f) + 1e-5f) * ONE_MINUS_LI_F;
    short* orow = Ab + (size_t)(b*T_ + t0 + t32)*1024 + wc*256 + (l&15);
    #pragma unroll
    for (int dc = 0; dc < 16; dc++){
      float o = acc1[dc][rg]*rinv[0][t32] - lam*acc2[dc][rg]*rinv[1][t32];
      orow[dc*16] = f2bf(o*scale);
    }
  }
}

// ---------------- launcher ----------------
extern "C" void kernel_launch(void* const* d_in, const int* in_sizes, int n_in,
                              void* d_out, int out_size, void* d_ws, size_t ws_size,
                              hipStream_t stream){
  const float* q   = (const float*)d_in[0];
  const float* k   = (const float*)d_in[1];
  const float* v   = (const float*)d_in[2];
  const float* Wq  = (const float*)d_in[3];
  const float* Wk  = (const float*)d_in[4];
  const float* Wv  = (const float*)d_in[5];
  const float* Wo  = (const float*)d_in[6];
  const float* lq1 = (const float*)d_in[7];
  const float* lk1 = (const float*)d_in[8];
  const float* lq2 = (const float*)d_in[9];
  const float* lk2 = (const float*)d_in[10];

  short* ws   = (short*)d_ws;
  short* qb   = ws;                              // [8192][1024]
  short* kb   = qb  + (size_t)8192*1024;         // [8192][1024]
  short* vb   = kb  + (size_t)8192*1024;         // [8192][1024]
  short* Wqb  = vb  + (size_t)8192*1024;         // [1024][1024]
  short* Wkb  = Wqb + (size_t)1024*1024;         // [512][1024]
  short* Wvb  = Wkb + (size_t)512*1024;          // [1024][1024]
  short* Wob  = Wvb + (size_t)1024*1024;         // [1024][1024]
  short* QPb  = Wob + (size_t)1024*1024;         // [8192][1024] scaled
  short* KPb  = QPb + (size_t)8192*1024;         // [8192][512]
  short* VPTb = KPb + (size_t)8192*512;          // [1024][8192]
  short* Ab   = qb;                              // alias: qb dead after projections

  auto cvt = [&](const float* in, short* out, size_t n){
    int n4 = (int)(n/4);
    int grid = (n4 + 255)/256; if (grid > 2048) grid = 2048;
    k_cvt<<<grid, 256, 0, stream>>>(in, out, n4);
  };
  cvt(q,  qb,  (size_t)8192*1024);
  cvt(k,  kb,  (size_t)8192*1024);
  cvt(v,  vb,  (size_t)8192*1024);
  cvt(Wq, Wqb, (size_t)1024*1024);
  cvt(Wk, Wkb, (size_t)512*1024);
  cvt(Wv, Wvb, (size_t)1024*1024);
  cvt(Wo, Wob, (size_t)1024*1024);

  // QP = (q Wq^T)*SCALING : M=8192 N=1024
  k_gemm<1><<<dim3(64, 8), 256, 0, stream>>>(qb, Wqb, QPb, 1024);
  // KP = k Wk^T : M=8192 N=512
  k_gemm<0><<<dim3(64, 4), 256, 0, stream>>>(kb, Wkb, KPb, 512);
  // VPT = Wv v^T : M=1024(d) N=8192(b*s)  -> VPT[d][bs]
  k_gemm<0><<<dim3(8, 64), 256, 0, stream>>>(Wvb, vb, VPTb, 8192);
  // fused dual-softmax attention + RMSNorm -> Ab (bf16)
  k_attn<<<dim3(128, 2), 512, 0, stream>>>(QPb, KPb, VPTb, lq1, lk1, lq2, lk2, Ab);
  // OUT = Ab Wo^T : M=8192 N=1024, fp32
  k_gemm<2><<<dim3(64, 8), 256, 0, stream>>>(Ab, Wob, d_out, 1024);
}

// Round 2
// 559.815 us; speedup vs baseline: 1.9907x; 1.9907x over previous
//
#include <hip/hip_runtime.h>
#include <stdint.h>
#include <stddef.h>

#define T_   4096
#define BT_  8192
#define SCALING_F      0.04419417382415922f
#define LAMBDA_INIT_F  0.7836057665316212f
#define ONE_MINUS_LI_F 0.2163942334683788f

typedef __attribute__((ext_vector_type(8))) short short8;
typedef __attribute__((ext_vector_type(4))) short short4v;
typedef __attribute__((ext_vector_type(4))) float f32x4;

__device__ __forceinline__ short f2bf(float f){
  uint32_t u = __float_as_uint(f);
  uint32_t r = (u + 0x7fffu + ((u >> 16) & 1u)) >> 16;   // RNE
  return (short)(uint16_t)r;
}

__device__ __forceinline__ f32x4 mfma16(short8 a, short8 b, f32x4 c){
  return __builtin_amdgcn_mfma_f32_16x16x32_bf16(a, b, c, 0, 0, 0);
}

__device__ __forceinline__ void stage16(short* lds, const short* g){
  __builtin_amdgcn_global_load_lds(
      (const __attribute__((address_space(1))) void*)g,
      (__attribute__((address_space(3))) void*)lds, 16, 0, 0);
}

// ---------------- fp32 -> bf16 convert ----------------
__global__ void k_cvt(const float* __restrict__ in, short* __restrict__ out, int n4){
  int i  = blockIdx.x*blockDim.x + threadIdx.x;
  int st = gridDim.x*blockDim.x;
  for (; i < n4; i += st){
    float4 v = ((const float4*)in)[i];
    short4v o;
    o.x = f2bf(v.x); o.y = f2bf(v.y); o.z = f2bf(v.z); o.w = f2bf(v.w);
    ((short4v*)out)[i] = o;
  }
}

// ---------------- NT GEMM: C[m][n] = sum_k A[m][k]*B[n][k], K=1024 fixed ----
// EPI: 0 = bf16 out, 1 = bf16 out * SCALING, 2 = fp32 out
template<int EPI>
__global__ __launch_bounds__(256, 3) void k_gemm(const short* __restrict__ A,
                                                 const short* __restrict__ Bm,
                                                 void* __restrict__ Cp, int ldc){
  __shared__ short As[128*32];
  __shared__ short Bs[128*32];
  const int tid = threadIdx.x;
  const int w = tid >> 6, l = tid & 63;
  const int m0 = blockIdx.x * 128;
  const int n0 = blockIdx.y * 128;
  const int wr = w >> 1, wc = w & 1;

  f32x4 acc[4][4] = {};

  const short* gA = A  + (size_t)(m0 + w*32 + (l>>2))*1024 + (l&3)*8;
  const short* gB = Bm + (size_t)(n0 + w*32 + (l>>2))*1024 + (l&3)*8;

  for (int k0 = 0; k0 < 1024; k0 += 32){
    stage16(As + w*1024,       gA + k0);
    stage16(As + w*1024 + 512, gA + 16*1024 + k0);
    stage16(Bs + w*1024,       gB + k0);
    stage16(Bs + w*1024 + 512, gB + 16*1024 + k0);
    __syncthreads();
    short8 aF[4], bF[4];
    #pragma unroll
    for (int i = 0; i < 4; i++){
      aF[i] = *(const short8*)&As[(wr*64 + i*16 + (l&15))*32 + (l>>4)*8];
      bF[i] = *(const short8*)&Bs[(wc*64 + i*16 + (l&15))*32 + (l>>4)*8];
    }
    #pragma unroll
    for (int i = 0; i < 4; i++)
      #pragma unroll
      for (int j = 0; j < 4; j++)
        acc[i][j] = mfma16(aF[i], bF[j], acc[i][j]);
    __syncthreads();
  }

  #pragma unroll
  for (int i = 0; i < 4; i++){
    #pragma unroll
    for (int j = 0; j < 4; j++){
      const size_t r0 = (size_t)m0 + wr*64 + i*16 + (l>>4)*4;
      const size_t c  = (size_t)n0 + wc*64 + j*16 + (l&15);
      #pragma unroll
      for (int rg = 0; rg < 4; rg++){
        float v = acc[i][j][rg];
        if (EPI == 2){
          ((float*)Cp)[(r0+rg)*(size_t)ldc + c] = v;
        } else {
          if (EPI == 1) v *= SCALING_F;
          ((short*)Cp)[(r0+rg)*(size_t)ldc + c] = f2bf(v);
        }
      }
    }
  }
}

// ---------------- fused dual-softmax attention + RMSNorm (v2) --------------
// grid: 256 blocks (XCD-swizzled -> (b, t-tile)), 512 thr / 8 waves.
// s-tile 64, 64 iters. K staged in LDS (dbuf, XOR-swizzled, prefetched one
// iter ahead via global_load_lds). V read global, dedup'd (wave = d-slice).
__global__ __launch_bounds__(512, 2) void k_attn(
    const short* __restrict__ QP, const short* __restrict__ KP,
    const short* __restrict__ VPT,
    const float* __restrict__ lq1, const float* __restrict__ lk1,
    const float* __restrict__ lq2, const float* __restrict__ lk2,
    short* __restrict__ Ab)
{
  __shared__ short Ks[2][64*512];   // 128 KB, swizzled: phys16Bchunk = logical ^ (row&7)
  __shared__ short Pl[2][32][72];   // exp(S), 72-short row pad (stride 9 chunks: conflict-free)
  __shared__ float lsum[8][16];
  __shared__ float rinv[2][32];
  __shared__ float ssq[8][32];

  // XCD-aware bijective swizzle (256 % 8 == 0)
  int wg = blockIdx.x;
  wg = (wg & 7)*32 + (wg >> 3);
  const int b  = wg >> 7;
  const int t0 = (wg & 127) * 32;

  const int tid = threadIdx.x;
  const int w = tid >> 6, l = tid & 63;

  // lambda
  float s1 = 0.f, s2 = 0.f;
  #pragma unroll
  for (int i = 0; i < 8; i++){
    int idx = l*8 + i;
    s1 += lq1[idx]*lk1[idx];
    s2 += lq2[idx]*lk2[idx];
  }
  #pragma unroll
  for (int off = 1; off < 64; off <<= 1){
    s1 += __shfl_xor(s1, off, 64);
    s2 += __shfl_xor(s2, off, 64);
  }
  const float lam = __expf(s1) - __expf(s2) + LAMBDA_INIT_F;

  // phase-1 role: rc=(h,tch), scb = s-col chunk pair
  const int rc = w >> 1, h = rc >> 1, tch = rc & 1, scb = w & 1;
  short8 qF[16];
  {
    const short* qb = QP + (size_t)(b*T_ + t0 + tch*16 + (l&15))*1024 + h*512 + (l>>4)*8;
    #pragma unroll
    for (int kk = 0; kk < 16; kk++) qF[kk] = *(const short8*)(qb + kk*32);
  }

  // phase-2 role: wave owns d-slice [w*128, w*128+128)
  f32x4 acc[4][8] = {};                // [rc = h*2+tc][dc]
  float lacc[4] = {0.f,0.f,0.f,0.f};

  const short* kpb = KP  + (size_t)(b*T_)*512;
  const short* vb  = VPT + (size_t)(w*128 + (l&15))*BT_ + b*T_ + (l>>4)*8;

  // swizzled-read lane constants
  const int jx = (l >> 4) ^ (l & 3);
  const int kx = (l >> 2) & 1;
  const int row0 = (2*scb)*16 + (l & 15);

  // prologue: stage K tile 0 into buf 0 (swizzled source)
  {
    short* kdst = &Ks[0][w*8*512];
    const short* ksrc = kpb + (size_t)(w*8)*512;
    #pragma unroll
    for (int j = 0; j < 8; j++)
      stage16(kdst + j*512, ksrc + (size_t)j*512 + ((l ^ j)*8));
  }
  __syncthreads();

  for (int st = 0; st < 64; st++){
    const int s0  = st*64;
    const int cur = st & 1;

    // ---- phase 1: S = Q.K^T from LDS, exp -> Pl ----
    f32x4 sa0 = {0.f,0.f,0.f,0.f}, sa1 = {0.f,0.f,0.f,0.f};
    {
      const short* p0 = &Ks[cur][0] + row0*512 + jx*8;
      const short* p1 = p0 + 16*512;
      #pragma unroll
      for (int kk = 0; kk < 16; kk++){
        short8 b0 = *(const short8*)(p0 + ((kk ^ kx) << 5));
        short8 b1 = *(const short8*)(p1 + ((kk ^ kx) << 5));
        sa0 = mfma16(qF[kk], b0, sa0);
        sa1 = mfma16(qF[kk], b1, sa1);
      }
    }

    // ---- issue next K tile stage (lands at iter-end __syncthreads) ----
    if (st + 1 < 64){
      short* kdst = &Ks[cur ^ 1][w*8*512];
      const short* ksrc = kpb + (size_t)((st+1)*64 + w*8)*512;
      #pragma unroll
      for (int j = 0; j < 8; j++)
        stage16(kdst + j*512, ksrc + (size_t)j*512 + ((l ^ j)*8));
    }

    // ---- exp + P write ----
    #pragma unroll
    for (int rg = 0; rg < 4; rg++){
      float e0 = __expf(sa0[rg]);
      float e1 = __expf(sa1[rg]);
      lacc[rg] += e0 + e1;
      int row = tch*16 + (l>>4)*4 + rg;
      Pl[h][row][(2*scb+0)*16 + (l&15)] = f2bf(e0);
      Pl[h][row][(2*scb+1)*16 + (l&15)] = f2bf(e1);
    }

    // mid barrier: LDS drained, K-stage loads stay in flight (vmcnt untouched)
    asm volatile("s_waitcnt lgkmcnt(0)" ::: "memory");
    __builtin_amdgcn_s_barrier();

    // ---- phase 2: O[rc] += P[rc].V for this wave's 128-wide d-slice ----
    #pragma unroll
    for (int ks = 0; ks < 2; ks++){
      short8 pa[4];
      #pragma unroll
      for (int rc2 = 0; rc2 < 4; rc2++)
        pa[rc2] = *(const short8*)&Pl[rc2>>1][(rc2&1)*16 + (l&15)][ks*32 + (l>>4)*8];
      #pragma unroll
      for (int dc = 0; dc < 8; dc++){
        short8 bV = *(const short8*)(vb + (size_t)dc*16*BT_ + s0 + ks*32);
        #pragma unroll
        for (int rc2 = 0; rc2 < 4; rc2++)
          acc[rc2][dc] = mfma16(pa[rc2], bV, acc[rc2][dc]);
      }
    }

    __syncthreads();   // vmcnt(0): staged K(i+1) landed; lgkm: P reads done
  }

  // ---- row sums -> 1/l ----
  #pragma unroll
  for (int off = 1; off < 16; off <<= 1)
    #pragma unroll
    for (int rg = 0; rg < 4; rg++) lacc[rg] += __shfl_xor(lacc[rg], off, 16);
  if ((l & 15) == 0){
    #pragma unroll
    for (int rg = 0; rg < 4; rg++) lsum[w][(l>>4)*4 + rg] = lacc[rg];
  }
  __syncthreads();
  if (tid < 64){
    int hh = tid >> 5, t = tid & 31;
    int rcc = hh*2 + (t >> 4), ric = t & 15;
    rinv[hh][t] = 1.0f / (lsum[rcc*2][ric] + lsum[rcc*2+1][ric]);
  }
  __syncthreads();

  // ---- combine pass 1: row sum-of-squares ----
  float ps[2][4] = {};
  #pragma unroll
  for (int tc = 0; tc < 2; tc++){
    #pragma unroll
    for (int dc = 0; dc < 8; dc++){
      #pragma unroll
      for (int rg = 0; rg < 4; rg++){
        int t32 = tc*16 + (l>>4)*4 + rg;
        float o = acc[tc][dc][rg]*rinv[0][t32] - lam*acc[2+tc][dc][rg]*rinv[1][t32];
        ps[tc][rg] += o*o;
      }
    }
  }
  #pragma unroll
  for (int tc = 0; tc < 2; tc++)
    #pragma unroll
    for (int off = 1; off < 16; off <<= 1)
      #pragma unroll
      for (int rg = 0; rg < 4; rg++) ps[tc][rg] += __shfl_xor(ps[tc][rg], off, 16);
  if ((l & 15) == 0){
    #pragma unroll
    for (int tc = 0; tc < 2; tc++)
      #pragma unroll
      for (int rg = 0; rg < 4; rg++) ssq[w][tc*16 + (l>>4)*4 + rg] = ps[tc][rg];
  }
  __syncthreads();

  // ---- combine pass 2: normalize + store ----
  #pragma unroll
  for (int tc = 0; tc < 2; tc++){
    #pragma unroll
    for (int rg = 0; rg < 4; rg++){
      int t32 = tc*16 + (l>>4)*4 + rg;
      float tot = 0.f;
      #pragma unroll
      for (int w8 = 0; w8 < 8; w8++) tot += ssq[w8][t32];
      float scale = rsqrtf(tot*(1.0f/1024.0f) + 1e-5f) * ONE_MINUS_LI_F;
      short* orow = Ab + (size_t)(b*T_ + t0 + t32)*1024 + w*128 + (l&15);
      #pragma unroll
      for (int dc = 0; dc < 8; dc++){
        float o = acc[tc][dc][rg]*rinv[0][t32] - lam*acc[2+tc][dc][rg]*rinv[1][t32];
        orow[dc*16] = f2bf(o*scale);
      }
    }
  }
}

// ---------------- launcher ----------------
extern "C" void kernel_launch(void* const* d_in, const int* in_sizes, int n_in,
                              void* d_out, int out_size, void* d_ws, size_t ws_size,
                              hipStream_t stream){
  const float* q   = (const float*)d_in[0];
  const float* k   = (const float*)d_in[1];
  const float* v   = (const float*)d_in[2];
  const float* Wq  = (const float*)d_in[3];
  const float* Wk  = (const float*)d_in[4];
  const float* Wv  = (const float*)d_in[5];
  const float* Wo  = (const float*)d_in[6];
  const float* lq1 = (const float*)d_in[7];
  const float* lk1 = (const float*)d_in[8];
  const float* lq2 = (const float*)d_in[9];
  const float* lk2 = (const float*)d_in[10];

  short* ws   = (short*)d_ws;
  short* qb   = ws;                              // [8192][1024]
  short* kb   = qb  + (size_t)8192*1024;         // [8192][1024]
  short* vb   = kb  + (size_t)8192*1024;         // [8192][1024]
  short* Wqb  = vb  + (size_t)8192*1024;         // [1024][1024]
  short* Wkb  = Wqb + (size_t)1024*1024;         // [512][1024]
  short* Wvb  = Wkb + (size_t)512*1024;          // [1024][1024]
  short* Wob  = Wvb + (size_t)1024*1024;         // [1024][1024]
  short* QPb  = Wob + (size_t)1024*1024;         // [8192][1024] scaled
  short* KPb  = QPb + (size_t)8192*1024;         // [8192][512]
  short* VPTb = KPb + (size_t)8192*512;          // [1024][8192]
  short* Ab   = qb;                              // alias: qb dead after projections

  auto cvt = [&](const float* in, short* out, size_t n){
    int n4 = (int)(n/4);
    int grid = (n4 + 255)/256; if (grid > 2048) grid = 2048;
    k_cvt<<<grid, 256, 0, stream>>>(in, out, n4);
  };
  cvt(q,  qb,  (size_t)8192*1024);
  cvt(k,  kb,  (size_t)8192*1024);
  cvt(v,  vb,  (size_t)8192*1024);
  cvt(Wq, Wqb, (size_t)1024*1024);
  cvt(Wk, Wkb, (size_t)512*1024);
  cvt(Wv, Wvb, (size_t)1024*1024);
  cvt(Wo, Wob, (size_t)1024*1024);

  // QP = (q Wq^T)*SCALING : M=8192 N=1024
  k_gemm<1><<<dim3(64, 8), 256, 0, stream>>>(qb, Wqb, QPb, 1024);
  // KP = k Wk^T : M=8192 N=512
  k_gemm<0><<<dim3(64, 4), 256, 0, stream>>>(kb, Wkb, KPb, 512);
  // VPT = Wv v^T : M=1024(d) N=8192(b*s)  -> VPT[d][bs]
  k_gemm<0><<<dim3(8, 64), 256, 0, stream>>>(Wvb, vb, VPTb, 8192);
  // fused dual-softmax attention + RMSNorm -> Ab (bf16)
  k_attn<<<dim3(256), 512, 0, stream>>>(QPb, KPb, VPTb, lq1, lk1, lq2, lk2, Ab);
  // OUT = Ab Wo^T : M=8192 N=1024, fp32
  k_gemm<2><<<dim3(64, 8), 256, 0, stream>>>(Ab, Wob, d_out, 1024);
}

// Round 3
// 452.465 us; speedup vs baseline: 2.4630x; 1.2373x over previous
//
#include <hip/hip_runtime.h>
#include <stdint.h>
#include <stddef.h>

#define T_   4096
#define BT_  8192
#define SCALING_F      0.04419417382415922f
#define LAMBDA_INIT_F  0.7836057665316212f
#define ONE_MINUS_LI_F 0.2163942334683788f

typedef __attribute__((ext_vector_type(8))) short short8;
typedef __attribute__((ext_vector_type(4))) short short4v;
typedef __attribute__((ext_vector_type(4))) float f32x4;

__device__ __forceinline__ short f2bf(float f){
  uint32_t u = __float_as_uint(f);
  uint32_t r = (u + 0x7fffu + ((u >> 16) & 1u)) >> 16;   // RNE
  return (short)(uint16_t)r;
}

__device__ __forceinline__ f32x4 mfma16(short8 a, short8 b, f32x4 c){
  return __builtin_amdgcn_mfma_f32_16x16x32_bf16(a, b, c, 0, 0, 0);
}

__device__ __forceinline__ void stage16(short* lds, const short* g){
  __builtin_amdgcn_global_load_lds(
      (const __attribute__((address_space(1))) void*)g,
      (__attribute__((address_space(3))) void*)lds, 16, 0, 0);
}

// ---------------- fp32 -> bf16 convert ----------------
__global__ void k_cvt(const float* __restrict__ in, short* __restrict__ out, int n4){
  int i  = blockIdx.x*blockDim.x + threadIdx.x;
  int st = gridDim.x*blockDim.x;
  for (; i < n4; i += st){
    float4 v = ((const float4*)in)[i];
    short4v o;
    o.x = f2bf(v.x); o.y = f2bf(v.y); o.z = f2bf(v.z); o.w = f2bf(v.w);
    ((short4v*)out)[i] = o;
  }
}

// ---------------- NT GEMM: C[m][n] = sum_k A[m][k]*B[n][k], K=1024 fixed ----
// EPI: 0 = bf16 out, 1 = bf16 out * SCALING, 2 = fp32 out
template<int EPI>
__global__ __launch_bounds__(256, 3) void k_gemm(const short* __restrict__ A,
                                                 const short* __restrict__ Bm,
                                                 void* __restrict__ Cp, int ldc){
  __shared__ short As[128*32];
  __shared__ short Bs[128*32];
  const int tid = threadIdx.x;
  const int w = tid >> 6, l = tid & 63;
  const int m0 = blockIdx.x * 128;
  const int n0 = blockIdx.y * 128;
  const int wr = w >> 1, wc = w & 1;

  f32x4 acc[4][4] = {};

  const short* gA = A  + (size_t)(m0 + w*32 + (l>>2))*1024 + (l&3)*8;
  const short* gB = Bm + (size_t)(n0 + w*32 + (l>>2))*1024 + (l&3)*8;

  for (int k0 = 0; k0 < 1024; k0 += 32){
    stage16(As + w*1024,       gA + k0);
    stage16(As + w*1024 + 512, gA + 16*1024 + k0);
    stage16(Bs + w*1024,       gB + k0);
    stage16(Bs + w*1024 + 512, gB + 16*1024 + k0);
    __syncthreads();
    short8 aF[4], bF[4];
    #pragma unroll
    for (int i = 0; i < 4; i++){
      aF[i] = *(const short8*)&As[(wr*64 + i*16 + (l&15))*32 + (l>>4)*8];
      bF[i] = *(const short8*)&Bs[(wc*64 + i*16 + (l&15))*32 + (l>>4)*8];
    }
    #pragma unroll
    for (int i = 0; i < 4; i++)
      #pragma unroll
      for (int j = 0; j < 4; j++)
        acc[i][j] = mfma16(aF[i], bF[j], acc[i][j]);
    __syncthreads();
  }

  #pragma unroll
  for (int i = 0; i < 4; i++){
    #pragma unroll
    for (int j = 0; j < 4; j++){
      const size_t r0 = (size_t)m0 + wr*64 + i*16 + (l>>4)*4;
      const size_t c  = (size_t)n0 + wc*64 + j*16 + (l&15);
      #pragma unroll
      for (int rg = 0; rg < 4; rg++){
        float v = acc[i][j][rg];
        if (EPI == 2){
          ((float*)Cp)[(r0+rg)*(size_t)ldc + c] = v;
        } else {
          if (EPI == 1) v *= SCALING_F;
          ((short*)Cp)[(r0+rg)*(size_t)ldc + c] = f2bf(v);
        }
      }
    }
  }
}

// ---------------- fused dual-softmax attention + RMSNorm (v3) --------------
// grid 256 (XCD-swizzled), 512 thr / 8 waves. s-tile 64, 64 iters.
// Q resident in LDS (64KB, swizzled). K single-buffer LDS (64KB, swizzled),
// staged for st+1 during phase-2 via global_load_lds (counted-vmcnt pattern).
// V prefetched to registers at phase-1 start (QK^T covers L2 latency).
__global__ __launch_bounds__(512, 2) void k_attn(
    const short* __restrict__ QP, const short* __restrict__ KP,
    const short* __restrict__ VPT,
    const float* __restrict__ lq1, const float* __restrict__ lk1,
    const float* __restrict__ lq2, const float* __restrict__ lk2,
    short* __restrict__ Ab)
{
  __shared__ short Ks[64*512];     // 64 KB, phys16Bchunk = logical ^ (srow&7)
  __shared__ short Qs[32*1024];    // 64 KB, phys16Bchunk = logical ^ (trow&7)
  __shared__ short Pl[2][32][72];  // exp(S), 9-chunk row stride
  __shared__ float lsum[8][16];
  __shared__ float rinv[2][32];
  __shared__ float ssq[8][32];

  // XCD-aware bijective swizzle (256 % 8 == 0)
  int wg = blockIdx.x;
  wg = (wg & 7)*32 + (wg >> 3);
  const int b  = wg >> 7;
  const int t0 = (wg & 127) * 32;

  const int tid = threadIdx.x;
  const int w = tid >> 6, l = tid & 63;

  // lambda
  float s1 = 0.f, s2 = 0.f;
  #pragma unroll
  for (int i = 0; i < 8; i++){
    int idx = l*8 + i;
    s1 += lq1[idx]*lk1[idx];
    s2 += lq2[idx]*lk2[idx];
  }
  #pragma unroll
  for (int off = 1; off < 64; off <<= 1){
    s1 += __shfl_xor(s1, off, 64);
    s2 += __shfl_xor(s2, off, 64);
  }
  const float lam = __expf(s1) - __expf(s2) + LAMBDA_INIT_F;

  // phase-1 role: (h, tch) x scb (s-col pair). phase-2 role: wave = 128-wide d-slice.
  const int rc = w >> 1, h = rc >> 1, tch = rc & 1, scb = w & 1;

  f32x4 acc[4][8] = {};                // [rc = h*2+tc][dc]
  float lacc[4] = {0.f,0.f,0.f,0.f};

  const short* kpb = KP  + (size_t)(b*T_)*512;
  const short* vbp = VPT + (size_t)(w*128 + (l&15))*BT_ + (size_t)b*T_ + (l>>4)*8;

  // swizzled-read lane constants
  const int jx = (l >> 4) ^ (l & 3);
  const int kx = (l >> 2) & 1;

  // ---- prologue: stage Q (whole tile) + K(0), swizzled sources ----
  {
    const short* qsrc = QP + (size_t)(b*T_ + t0)*1024;
    #pragma unroll
    for (int j = 0; j < 4; j++){
      int r = w*4 + j;
      #pragma unroll
      for (int h2 = 0; h2 < 2; h2++)
        stage16(&Qs[r*1024 + h2*512],
                qsrc + (size_t)r*1024 + (h2*64 + (l ^ (r & 7)))*8);
    }
    #pragma unroll
    for (int j = 0; j < 8; j++)
      stage16(&Ks[(w*8 + j)*512], kpb + (size_t)(w*8 + j)*512 + ((l ^ j)*8));
  }
  __syncthreads();

  const short* qp0 = &Qs[(tch*16 + (l&15))*1024 + h*512 + jx*8];
  const short* kp0 = &Ks[(scb*32 + (l&15))*512 + jx*8];
  const short* kp1 = kp0 + 16*512;

  for (int st = 0; st < 64; st++){
    const int s0 = st*64;

    // ---- V prefetch into registers (consumed in phase 2) ----
    short8 varr[16];
    #pragma unroll
    for (int dc = 0; dc < 8; dc++)
      #pragma unroll
      for (int ks = 0; ks < 2; ks++)
        varr[dc*2 + ks] = *(const short8*)(vbp + (size_t)dc*16*BT_ + s0 + ks*32);
    __builtin_amdgcn_sched_barrier(0);   // pin issue before QK^T

    // ---- phase 1: S = Q.K^T (Q,K from swizzled LDS), exp -> Pl ----
    f32x4 sa0 = {0.f,0.f,0.f,0.f}, sa1 = {0.f,0.f,0.f,0.f};
    #pragma unroll
    for (int kk = 0; kk < 16; kk++){
      const int ko = ((kk ^ kx) << 5);
      short8 qf = *(const short8*)(qp0 + ko);
      short8 b0 = *(const short8*)(kp0 + ko);
      short8 b1 = *(const short8*)(kp1 + ko);
      sa0 = mfma16(qf, b0, sa0);
      sa1 = mfma16(qf, b1, sa1);
    }

    #pragma unroll
    for (int rg = 0; rg < 4; rg++){
      float e0 = __expf(sa0[rg]);
      float e1 = __expf(sa1[rg]);
      lacc[rg] += e0 + e1;
      int row = tch*16 + (l>>4)*4 + rg;
      Pl[h][row][(2*scb+0)*16 + (l&15)] = f2bf(e0);
      Pl[h][row][(2*scb+1)*16 + (l&15)] = f2bf(e1);
    }

    // mid barrier: own LDS ops drained; vmcnt untouched (V loads may still fly)
    asm volatile("s_waitcnt lgkmcnt(0)" ::: "memory");
    __builtin_amdgcn_s_barrier();

    // ---- phase 2: issue K(st+1) DMA, then P.V from registers ----
    if (st + 1 < 64){
      const short* ksrc = kpb + (size_t)((st+1)*64 + w*8)*512;
      #pragma unroll
      for (int j = 0; j < 8; j++)
        stage16(&Ks[(w*8 + j)*512], ksrc + (size_t)j*512 + ((l ^ j)*8));
    }

    #pragma unroll
    for (int ks = 0; ks < 2; ks++){
      short8 pa[4];
      #pragma unroll
      for (int rc2 = 0; rc2 < 4; rc2++)
        pa[rc2] = *(const short8*)&Pl[rc2>>1][(rc2&1)*16 + (l&15)][ks*32 + (l>>4)*8];
      #pragma unroll
      for (int dc = 0; dc < 8; dc++)
        #pragma unroll
        for (int rc2 = 0; rc2 < 4; rc2++)
          acc[rc2][dc] = mfma16(pa[rc2], varr[dc*2 + ks], acc[rc2][dc]);
    }

    __syncthreads();   // drains vmcnt(0): K(st+1) landed; lgkm: P reads done
  }

  // ---- row sums -> 1/l ----
  #pragma unroll
  for (int off = 1; off < 16; off <<= 1)
    #pragma unroll
    for (int rg = 0; rg < 4; rg++) lacc[rg] += __shfl_xor(lacc[rg], off, 16);
  if ((l & 15) == 0){
    #pragma unroll
    for (int rg = 0; rg < 4; rg++) lsum[w][(l>>4)*4 + rg] = lacc[rg];
  }
  __syncthreads();
  if (tid < 64){
    int hh = tid >> 5, t = tid & 31;
    int rcc = hh*2 + (t >> 4), ric = t & 15;
    rinv[hh][t] = 1.0f / (lsum[rcc*2][ric] + lsum[rcc*2+1][ric]);
  }
  __syncthreads();

  // ---- combine pass 1: row sum-of-squares ----
  float ps[2][4] = {};
  #pragma unroll
  for (int tc = 0; tc < 2; tc++){
    #pragma unroll
    for (int dc = 0; dc < 8; dc++){
      #pragma unroll
      for (int rg = 0; rg < 4; rg++){
        int t32 = tc*16 + (l>>4)*4 + rg;
        float o = acc[tc][dc][rg]*rinv[0][t32] - lam*acc[2+tc][dc][rg]*rinv[1][t32];
        ps[tc][rg] += o*o;
      }
    }
  }
  #pragma unroll
  for (int tc = 0; tc < 2; tc++)
    #pragma unroll
    for (int off = 1; off < 16; off <<= 1)
      #pragma unroll
      for (int rg = 0; rg < 4; rg++) ps[tc][rg] += __shfl_xor(ps[tc][rg], off, 16);
  if ((l & 15) == 0){
    #pragma unroll
    for (int tc = 0; tc < 2; tc++)
      #pragma unroll
      for (int rg = 0; rg < 4; rg++) ssq[w][tc*16 + (l>>4)*4 + rg] = ps[tc][rg];
  }
  __syncthreads();

  // ---- combine pass 2: normalize + store ----
  #pragma unroll
  for (int tc = 0; tc < 2; tc++){
    #pragma unroll
    for (int rg = 0; rg < 4; rg++){
      int t32 = tc*16 + (l>>4)*4 + rg;
      float tot = 0.f;
      #pragma unroll
      for (int w8 = 0; w8 < 8; w8++) tot += ssq[w8][t32];
      float scale = rsqrtf(tot*(1.0f/1024.0f) + 1e-5f) * ONE_MINUS_LI_F;
      short* orow = Ab + (size_t)(b*T_ + t0 + t32)*1024 + w*128 + (l&15);
      #pragma unroll
      for (int dc = 0; dc < 8; dc++){
        float o = acc[tc][dc][rg]*rinv[0][t32] - lam*acc[2+tc][dc][rg]*rinv[1][t32];
        orow[dc*16] = f2bf(o*scale);
      }
    }
  }
}

// ---------------- launcher ----------------
extern "C" void kernel_launch(void* const* d_in, const int* in_sizes, int n_in,
                              void* d_out, int out_size, void* d_ws, size_t ws_size,
                              hipStream_t stream){
  const float* q   = (const float*)d_in[0];
  const float* k   = (const float*)d_in[1];
  const float* v   = (const float*)d_in[2];
  const float* Wq  = (const float*)d_in[3];
  const float* Wk  = (const float*)d_in[4];
  const float* Wv  = (const float*)d_in[5];
  const float* Wo  = (const float*)d_in[6];
  const float* lq1 = (const float*)d_in[7];
  const float* lk1 = (const float*)d_in[8];
  const float* lq2 = (const float*)d_in[9];
  const float* lk2 = (const float*)d_in[10];

  short* ws   = (short*)d_ws;
  short* qb   = ws;                              // [8192][1024]
  short* kb   = qb  + (size_t)8192*1024;         // [8192][1024]
  short* vb   = kb  + (size_t)8192*1024;         // [8192][1024]
  short* Wqb  = vb  + (size_t)8192*1024;         // [1024][1024]
  short* Wkb  = Wqb + (size_t)1024*1024;         // [512][1024]
  short* Wvb  = Wkb + (size_t)512*1024;          // [1024][1024]
  short* Wob  = Wvb + (size_t)1024*1024;         // [1024][1024]
  short* QPb  = Wob + (size_t)1024*1024;         // [8192][1024] scaled
  short* KPb  = QPb + (size_t)8192*1024;         // [8192][512]
  short* VPTb = KPb + (size_t)8192*512;          // [1024][8192]
  short* Ab   = qb;                              // alias: qb dead after projections

  auto cvt = [&](const float* in, short* out, size_t n){
    int n4 = (int)(n/4);
    int grid = (n4 + 255)/256; if (grid > 2048) grid = 2048;
    k_cvt<<<grid, 256, 0, stream>>>(in, out, n4);
  };
  cvt(q,  qb,  (size_t)8192*1024);
  cvt(k,  kb,  (size_t)8192*1024);
  cvt(v,  vb,  (size_t)8192*1024);
  cvt(Wq, Wqb, (size_t)1024*1024);
  cvt(Wk, Wkb, (size_t)512*1024);
  cvt(Wv, Wvb, (size_t)1024*1024);
  cvt(Wo, Wob, (size_t)1024*1024);

  // QP = (q Wq^T)*SCALING : M=8192 N=1024
  k_gemm<1><<<dim3(64, 8), 256, 0, stream>>>(qb, Wqb, QPb, 1024);
  // KP = k Wk^T : M=8192 N=512
  k_gemm<0><<<dim3(64, 4), 256, 0, stream>>>(kb, Wkb, KPb, 512);
  // VPT = Wv v^T : M=1024(d) N=8192(b*s)  -> VPT[d][bs]
  k_gemm<0><<<dim3(8, 64), 256, 0, stream>>>(Wvb, vb, VPTb, 8192);
  // fused dual-softmax attention + RMSNorm -> Ab (bf16)
  k_attn<<<dim3(256), 512, 0, stream>>>(QPb, KPb, VPTb, lq1, lk1, lq2, lk2, Ab);
  // OUT = Ab Wo^T : M=8192 N=1024, fp32
  k_gemm<2><<<dim3(64, 8), 256, 0, stream>>>(Ab, Wob, d_out, 1024);
}